// Round 1
// baseline (398.973 us; speedup 1.0000x reference)
//
#include <hip/hip_runtime.h>

// ---------------------------------------------------------------------------
// MultiScaleResidualVectorQuantize: 4-stage residual VQ, strides (8,4,2,1)
// z:(16,512,4096) f32; in_w:(4,8,512); in_b:(4,8); out_w:(4,512,8);
// out_b:(4,512); codebooks:(4,1024,8)
//
// Algebraic restructure: e_i = P_i - sum_{j<i} (M_ij q_j + v_ij) with
// P_i = iw_i * pool_i(z) + ib_i,  M_ij = iw_i*ow_j (8x8),  v_ij = iw_i*ob_j.
// One read of z, one write of z_q; cascade entirely in C=8 space.
// ---------------------------------------------------------------------------

constexpr int B = 16, D = 512, T = 4096, C = 8, K = 1024, NS = 4;

// output offsets (floats, concatenated in reference return order)
constexpr long long OUT_ZQ     = 0;                       // 16*512*4096
constexpr long long OUT_LAT    = 33554432LL;              // 16*32*4096
constexpr long long OUT_COMMIT = OUT_LAT + 2097152LL;     // 35651584
constexpr long long OUT_CBL    = OUT_COMMIT + 1;          // 35651585
constexpr long long OUT_CODES0 = OUT_CBL + 1;             // 35651586

// workspace offsets (floats)
constexpr long long WS_CBREC = 0;                 // 4*1024*12 = 49152 (-2*cbn[8], cn2, pad3)
constexpr long long WS_OBS   = 49152;             // 512 (sum of out biases)
constexpr long long WS_LOSS  = 49664;             // 1
constexpr long long WS_CORR  = 49696;             // doubles: 6 pairs * 72 = 1152 d = 2304 f
constexpr long long WS_P0    = 52224;             // 8192*8
constexpr long long WS_P1    = WS_P0 + 65536;
constexpr long long WS_P2    = WS_P1 + 131072;
constexpr long long WS_P3    = WS_P2 + 262144;
constexpr long long WS_Q0    = WS_P3 + 524288;
constexpr long long WS_Q1    = WS_Q0 + 65536;
constexpr long long WS_Q2    = WS_Q1 + 131072;
constexpr long long WS_Q3    = WS_Q2 + 262144;    // ends 2,018,304 floats (~8.1 MB)

// ---------------------------------------------------------------------------
// k_prep: normalized codebook records, M/v correction terms (f64), sum-bias,
// zero loss accumulator. One block.
// ---------------------------------------------------------------------------
__global__ __launch_bounds__(256) void k_prep(
    const float* __restrict__ in_w, const float* __restrict__ in_b,
    const float* __restrict__ out_w, const float* __restrict__ out_b,
    const float* __restrict__ cb, float* __restrict__ ws)
{
    int tid = threadIdx.x;
    if (tid == 0) ws[WS_LOSS] = 0.f;

    for (int d = tid; d < D; d += 256) {
        ws[WS_OBS + d] = out_b[d] + out_b[512 + d] + out_b[1024 + d] + out_b[1536 + d];
    }

    for (int idx = tid; idx < NS * K; idx += 256) {
        const float* c = cb + (long long)idx * 8;
        float n2 = 0.f;
        for (int k = 0; k < 8; k++) n2 += c[k] * c[k];
        float den = fmaxf(sqrtf(n2), 1e-12f);
        float cn[8];
        for (int k = 0; k < 8; k++) cn[k] = c[k] / den;
        float cn2 = 0.f;
        for (int k = 0; k < 8; k++) cn2 += cn[k] * cn[k];
        float* r = ws + WS_CBREC + (long long)idx * 12;
        for (int k = 0; k < 8; k++) r[k] = -2.0f * cn[k];   // exact *2
        r[8] = cn2; r[9] = 0.f; r[10] = 0.f; r[11] = 0.f;
    }

    // correction pairs p: (i,j) = (1,0),(2,0),(2,1),(3,0),(3,1),(3,2)
    double* corr = (double*)(ws + WS_CORR);
    for (int f = tid; f < 6 * 72; f += 256) {
        int p = f / 72, idx = f % 72;
        int i, j;
        if (p == 0) { i = 1; j = 0; }
        else if (p < 3) { i = 2; j = p - 1; }
        else { i = 3; j = p - 3; }
        double acc = 0.0;
        if (idx < 64) {
            int ci = idx >> 3, cc = idx & 7;
            const float* wi = in_w + (long long)(i * 8 + ci) * 512;
            const float* wo = out_w + (long long)j * 4096;      // [d][8]
            for (int d = 0; d < 512; d++) acc += (double)wi[d] * (double)wo[d * 8 + cc];
        } else {
            int ci = idx - 64;
            const float* wi = in_w + (long long)(i * 8 + ci) * 512;
            const float* bo = out_b + (long long)j * 512;
            for (int d = 0; d < 512; d++) acc += (double)wi[d] * (double)bo[d];
        }
        corr[p * 72 + idx] = acc;
    }
}

// ---------------------------------------------------------------------------
// k_pool_proj: one pass over z. Block = (b, 256-t span), 512 thr = 8 dsegs x
// 64 lanes (each lane owns 4 consecutive t). Hierarchical pooled projections
// for all 4 stages, LDS tree reduce over dsegs, write P0..P3 (+bias).
// ---------------------------------------------------------------------------
__global__ __launch_bounds__(512) void k_pool_proj(
    const float* __restrict__ z, const float* __restrict__ in_w,
    const float* __restrict__ in_b, float* __restrict__ ws)
{
    __shared__ float red[8][32][64];   // 64 KB
    int tid = threadIdx.x;
    int lane = tid & 63;
    int wv = __builtin_amdgcn_readfirstlane(tid >> 6);   // dseg, wave-uniform
    int b = blockIdx.x;
    int t0 = blockIdx.y * 256;

    const float* zrow = z + ((long long)b * D) * T + t0 + lane * 4;

    float a3[4][8] = {}; // stage3 (stride1), per-position
    float a2[2][8] = {}; // stage2 (stride2)
    float a1[8]    = {}; // stage1 (stride4)
    float a0[8]    = {}; // stage0 (stride8), partial (pairs of lanes combine)

    for (int dd = 0; dd < 64; dd++) {
        int d = wv * 64 + dd;
        float4 v = *(const float4*)(zrow + (long long)d * T);
        float s2a = v.x + v.y, s2b = v.z + v.w;
        float s4 = s2a + s2b;
#pragma unroll
        for (int c = 0; c < 8; c++) {
            float w3 = in_w[(3 * 8 + c) * 512 + d];
            float w2 = in_w[(2 * 8 + c) * 512 + d];
            float w1 = in_w[(1 * 8 + c) * 512 + d];
            float w0 = in_w[(0 * 8 + c) * 512 + d];
            a3[0][c] = fmaf(w3, v.x, a3[0][c]);
            a3[1][c] = fmaf(w3, v.y, a3[1][c]);
            a3[2][c] = fmaf(w3, v.z, a3[2][c]);
            a3[3][c] = fmaf(w3, v.w, a3[3][c]);
            a2[0][c] = fmaf(w2, s2a, a2[0][c]);
            a2[1][c] = fmaf(w2, s2b, a2[1][c]);
            a1[c]    = fmaf(w1, s4, a1[c]);
            a0[c]    = fmaf(w0, s4, a0[c]);
        }
    }

    // round 1: stage3 (32 slots)
#pragma unroll
    for (int pos = 0; pos < 4; pos++)
#pragma unroll
        for (int c = 0; c < 8; c++)
            red[wv][pos * 8 + c][lane] = a3[pos][c];
    __syncthreads();
    for (int o = tid; o < 2048; o += 512) {
        int ln = o & 63, s = o >> 6;
        float sum = 0.f;
#pragma unroll
        for (int w = 0; w < 8; w++) sum += red[w][s][ln];
        int pos = s >> 3, c = s & 7;
        int tp = t0 + ln * 4 + pos;
        ws[WS_P3 + ((long long)b * 4096 + tp) * 8 + c] = sum + in_b[3 * 8 + c];
    }
    __syncthreads();

    // round 2: stage2 (16 slots), stage1 (8), stage0 (8)
#pragma unroll
    for (int pos = 0; pos < 2; pos++)
#pragma unroll
        for (int c = 0; c < 8; c++)
            red[wv][pos * 8 + c][lane] = a2[pos][c];
#pragma unroll
    for (int c = 0; c < 8; c++) {
        red[wv][16 + c][lane] = a1[c];
        red[wv][24 + c][lane] = a0[c];
    }
    __syncthreads();
    for (int o = tid; o < 2048; o += 512) {
        int ln = o & 63, s = o >> 6;
        if (s < 16) {
            float sum = 0.f;
#pragma unroll
            for (int w = 0; w < 8; w++) sum += red[w][s][ln];
            int pos = s >> 3, c = s & 7;
            int tp = (t0 >> 1) + ln * 2 + pos;
            ws[WS_P2 + ((long long)b * 2048 + tp) * 8 + c] = sum * 0.5f + in_b[2 * 8 + c];
        } else if (s < 24) {
            int c = s - 16;
            float sum = 0.f;
#pragma unroll
            for (int w = 0; w < 8; w++) sum += red[w][s][ln];
            int tp = (t0 >> 2) + ln;
            ws[WS_P1 + ((long long)b * 1024 + tp) * 8 + c] = sum * 0.25f + in_b[8 + c];
        } else {
            if (ln & 1) continue;
            int c = s - 24;
            float sum = 0.f;
#pragma unroll
            for (int w = 0; w < 8; w++) sum += red[w][s][ln] + red[w][s][ln + 1];
            int tp = (t0 >> 3) + (ln >> 1);
            ws[WS_P0 + ((long long)b * 512 + tp) * 8 + c] = sum * 0.125f + in_b[c];
        }
    }
}

// ---------------------------------------------------------------------------
// k_vq<STAGE>: block = 64 vectors x 4 code-chunk waves. e from P minus f64
// corrections, normalize, argmin over 1024 codes (first-index tie rule),
// write q/codes/latents, accumulate loss.
// ---------------------------------------------------------------------------
template <int STAGE>
__global__ __launch_bounds__(256) void k_vq(
    const float* __restrict__ cb, float* __restrict__ ws, float* __restrict__ out)
{
    constexpr int TS = 512 << STAGE;
    constexpr long long PBASE = (STAGE == 0) ? WS_P0 : (STAGE == 1) ? WS_P1 : (STAGE == 2) ? WS_P2 : WS_P3;
    constexpr long long QBASE = (STAGE == 0) ? WS_Q0 : (STAGE == 1) ? WS_Q1 : (STAGE == 2) ? WS_Q2 : WS_Q3;

    int tid = threadIdx.x;
    int lane = tid & 63;
    int w = __builtin_amdgcn_readfirstlane(tid >> 6);

    long long v = (long long)blockIdx.x * 64 + lane;
    int b = (int)(v >> (9 + STAGE));
    int tp = (int)(v & (TS - 1));

    float e[8];
    const float* P = ws + PBASE + v * 8;
#pragma unroll
    for (int c = 0; c < 8; c++) e[c] = P[c];

    if (STAGE > 0) {
        double ed[8];
#pragma unroll
        for (int c = 0; c < 8; c++) ed[c] = (double)e[c];
        const double* corr = (const double*)(ws + WS_CORR);
        constexpr int pbase = (STAGE == 1) ? 0 : (STAGE == 2) ? 1 : 3;
#pragma unroll
        for (int j = 0; j < STAGE; j++) {
            const double* M = corr + (pbase + j) * 72;
            long long qb = (j == 0) ? WS_Q0 : (j == 1) ? WS_Q1 : WS_Q2;
            int tj = tp >> (STAGE - j);
            long long vj = ((long long)b << (9 + j)) + tj;
            const float* ql = ws + qb + vj * 8;
#pragma unroll
            for (int c = 0; c < 8; c++) {
                double acc = M[64 + c];
#pragma unroll
                for (int cc = 0; cc < 8; cc++) acc += M[c * 8 + cc] * (double)ql[cc];
                ed[c] -= acc;
            }
        }
#pragma unroll
        for (int c = 0; c < 8; c++) e[c] = (float)ed[c];
    }

    // normalize (F.normalize semantics: x / max(||x||, 1e-12))
    float n2 = 0.f;
#pragma unroll
    for (int c = 0; c < 8; c++) n2 = fmaf(e[c], e[c], n2);
    float den = fmaxf(sqrtf(n2), 1e-12f);
    float inv = 1.0f / den;
    float en[8];
#pragma unroll
    for (int c = 0; c < 8; c++) en[c] = e[c] * inv;
    float en2 = 0.f;
#pragma unroll
    for (int c = 0; c < 8; c++) en2 = fmaf(en[c], en[c], en2);

    // search this wave's 256-code chunk; uniform (scalar) code stream
    const float* rec = ws + WS_CBREC + (long long)STAGE * K * 12 + (long long)w * 256 * 12;
    float best = 3.0e38f;
    int bidx = 0;
    for (int jt = 0; jt < 256; jt++) {
        const float* r = rec + jt * 12;
        float acc = en2;
#pragma unroll
        for (int c = 0; c < 8; c++) acc = fmaf(r[c], en[c], acc);  // en2 - 2*dot
        float dist = acc + r[8];                                   // + cn2
        if (dist < best) { best = dist; bidx = w * 256 + jt; }
    }

    __shared__ float sb[4][64];
    __shared__ int si[4][64];
    sb[w][lane] = best;
    si[w][lane] = bidx;
    __syncthreads();

    if (tid < 64) {
        float bd = sb[0][lane];
        int bj = si[0][lane];
#pragma unroll
        for (int ww = 1; ww < 4; ww++) {
            float d2 = sb[ww][lane];
            int j2 = si[ww][lane];
            if (d2 < bd || (d2 == bd && j2 < bj)) { bd = d2; bj = j2; }
        }
        // unnormalized codebook lookup
        const float* qc = cb + ((long long)STAGE * K + bj) * 8;
        float qv[8];
#pragma unroll
        for (int c = 0; c < 8; c++) qv[c] = qc[c];
        float* qo = ws + QBASE + v * 8;
#pragma unroll
        for (int c = 0; c < 8; c++) qo[c] = qv[c];

        constexpr long long CODE_OFF = OUT_CODES0 + ((STAGE >= 1) ? 8192 : 0)
                                       + ((STAGE >= 2) ? 16384 : 0) + ((STAGE >= 3) ? 32768 : 0);
        out[CODE_OFF + v] = (float)bj;

        // commit/cb loss (identical values): mean over (c,t), then batch
        float l = 0.f;
#pragma unroll
        for (int c = 0; c < 8; c++) { float dq = e[c] - qv[c]; l = fmaf(dq, dq, l); }
#pragma unroll
        for (int off = 32; off >= 1; off >>= 1) l += __shfl_down(l, off);
        if (lane == 0) atomicAdd(ws + WS_LOSS, l * (1.0f / (8.0f * (float)TS * (float)B)));

        // latents: z_e repeated to full T
        constexpr int S = 8 >> STAGE;
        long long lat = OUT_LAT + ((long long)b * 32 + STAGE * 8) * T + (long long)tp * S;
#pragma unroll
        for (int c = 0; c < 8; c++)
            for (int k = 0; k < S; k++)
                out[lat + (long long)c * T + k] = e[c];
    }
}

// ---------------------------------------------------------------------------
// k_zq: z_q[b,d,t] = sum_i (ow_i q_i[t>>k_i]) + sum_i ob_i. Hierarchical
// (15 FMA/elem). Wave = (16-d group, 64 t1-blocks); lane stores 8 t as 2xfloat4.
// ---------------------------------------------------------------------------
__global__ __launch_bounds__(256) void k_zq(
    const float* __restrict__ out_w, const float* __restrict__ ws, float* __restrict__ out)
{
    int tid = threadIdx.x;
    int lane = tid & 63;
    int w = __builtin_amdgcn_readfirstlane(tid >> 6);
    int gw = blockIdx.x * 4 + w;           // 4096 waves
    int dgrp = gw & 31;                    // 16 d each
    int t1g = gw >> 5;                     // 128 chunks of 64 t1-blocks
    int t1 = t1g * 64 + lane;              // global t1-block id (0..8191)
    int b = t1 >> 9;
    int t1l = t1 & 511;

    float q0[8], q1a[2][8], q2a[4][8], q3a[8][8];
    {
        const float* Q = ws + WS_Q0 + ((long long)b * 512 + t1l) * 8;
#pragma unroll
        for (int c = 0; c < 8; c++) q0[c] = Q[c];
    }
    {
        const float* Q = ws + WS_Q1 + ((long long)b * 1024 + t1l * 2) * 8;
#pragma unroll
        for (int j = 0; j < 2; j++)
#pragma unroll
            for (int c = 0; c < 8; c++) q1a[j][c] = Q[j * 8 + c];
    }
    {
        const float* Q = ws + WS_Q2 + ((long long)b * 2048 + t1l * 4) * 8;
#pragma unroll
        for (int j = 0; j < 4; j++)
#pragma unroll
            for (int c = 0; c < 8; c++) q2a[j][c] = Q[j * 8 + c];
    }
    {
        const float* Q = ws + WS_Q3 + ((long long)b * 4096 + t1l * 8) * 8;
#pragma unroll
        for (int j = 0; j < 8; j++)
#pragma unroll
            for (int c = 0; c < 8; c++) q3a[j][c] = Q[j * 8 + c];
    }

    for (int dl = 0; dl < 16; dl++) {
        int d = dgrp * 16 + dl;
        const float* w0 = out_w + 0 * 4096 + d * 8;
        const float* w1 = out_w + 1 * 4096 + d * 8;
        const float* w2 = out_w + 2 * 4096 + d * 8;
        const float* w3 = out_w + 3 * 4096 + d * 8;
        float base0 = ws[WS_OBS + d];
#pragma unroll
        for (int c = 0; c < 8; c++) base0 = fmaf(w0[c], q0[c], base0);
        float res[8];
#pragma unroll
        for (int j1 = 0; j1 < 2; j1++) {
            float b1 = base0;
#pragma unroll
            for (int c = 0; c < 8; c++) b1 = fmaf(w1[c], q1a[j1][c], b1);
#pragma unroll
            for (int j2 = 0; j2 < 2; j2++) {
                float b2 = b1;
#pragma unroll
                for (int c = 0; c < 8; c++) b2 = fmaf(w2[c], q2a[j1 * 2 + j2][c], b2);
#pragma unroll
                for (int j3 = 0; j3 < 2; j3++) {
                    int tl = j1 * 4 + j2 * 2 + j3;
                    float b3 = b2;
#pragma unroll
                    for (int c = 0; c < 8; c++) b3 = fmaf(w3[c], q3a[tl][c], b3);
                    res[tl] = b3;
                }
            }
        }
        float* o = out + OUT_ZQ + ((long long)b * 512 + d) * T + (long long)t1l * 8;
        *(float4*)(o)     = make_float4(res[0], res[1], res[2], res[3]);
        *(float4*)(o + 4) = make_float4(res[4], res[5], res[6], res[7]);
    }

    if (blockIdx.x == 0 && tid == 0) {
        float L = ws[WS_LOSS];
        out[OUT_COMMIT] = L;
        out[OUT_CBL]    = L;   // identical by construction
    }
}

// ---------------------------------------------------------------------------
extern "C" void kernel_launch(void* const* d_in, const int* in_sizes, int n_in,
                              void* d_out, int out_size, void* d_ws, size_t ws_size,
                              hipStream_t stream)
{
    const float* z     = (const float*)d_in[0];
    const float* in_w  = (const float*)d_in[1];
    const float* in_b  = (const float*)d_in[2];
    const float* out_w = (const float*)d_in[3];
    const float* out_b = (const float*)d_in[4];
    const float* cb    = (const float*)d_in[5];
    float* out = (float*)d_out;
    float* ws  = (float*)d_ws;

    k_prep<<<dim3(1), dim3(256), 0, stream>>>(in_w, in_b, out_w, out_b, cb, ws);
    k_pool_proj<<<dim3(16, 16), dim3(512), 0, stream>>>(z, in_w, in_b, ws);
    k_vq<0><<<dim3(8192 / 64), dim3(256), 0, stream>>>(cb, ws, out);
    k_vq<1><<<dim3(16384 / 64), dim3(256), 0, stream>>>(cb, ws, out);
    k_vq<2><<<dim3(32768 / 64), dim3(256), 0, stream>>>(cb, ws, out);
    k_vq<3><<<dim3(65536 / 64), dim3(256), 0, stream>>>(cb, ws, out);
    k_zq<<<dim3(1024), dim3(256), 0, stream>>>(out_w, ws, out);
}

// Round 2
// 326.031 us; speedup vs baseline: 1.2237x; 1.2237x over previous
//
#include <hip/hip_runtime.h>

// ---------------------------------------------------------------------------
// MultiScaleResidualVectorQuantize: 4-stage residual VQ, strides (8,4,2,1)
// z:(16,512,4096) f32; in_w:(4,8,512); in_b:(4,8); out_w:(4,512,8);
// out_b:(4,512); codebooks:(4,1024,8)
//
// Algebraic restructure: e_i = P_i - sum_{j<i} (M_ij q_j + v_ij) with
// P_i = iw_i * pool_i(z) + ib_i,  M_ij = iw_i*ow_j (8x8),  v_ij = iw_i*ob_j.
// One read of z, one write of z_q; cascade entirely in C=8 space.
// ---------------------------------------------------------------------------

constexpr int B = 16, D = 512, T = 4096, C = 8, K = 1024, NS = 4;

// output offsets (floats, concatenated in reference return order)
constexpr long long OUT_ZQ     = 0;                       // 16*512*4096
constexpr long long OUT_LAT    = 33554432LL;              // 16*32*4096
constexpr long long OUT_COMMIT = OUT_LAT + 2097152LL;     // 35651584
constexpr long long OUT_CBL    = OUT_COMMIT + 1;          // 35651585
constexpr long long OUT_CODES0 = OUT_CBL + 1;             // 35651586

// workspace offsets (floats)
constexpr long long WS_CBREC = 0;                 // 4*1024*12 = 49152 (-2*cbn[8], cn2, pad3)
constexpr long long WS_OBS   = 49152;             // 512 (sum of out biases)
constexpr long long WS_LOSS  = 49664;             // 1
constexpr long long WS_CORR  = 49696;             // doubles: 6 pairs * 72 = 1152 d = 2304 f
constexpr long long WS_P0    = 52224;             // 8192*8
constexpr long long WS_P1    = WS_P0 + 65536;
constexpr long long WS_P2    = WS_P1 + 131072;
constexpr long long WS_P3    = WS_P2 + 262144;
constexpr long long WS_Q0    = WS_P3 + 524288;
constexpr long long WS_Q1    = WS_Q0 + 65536;
constexpr long long WS_Q2    = WS_Q1 + 131072;
constexpr long long WS_Q3    = WS_Q2 + 262144;    // ends 2,018,304 floats (~8.1 MB)

// ---------------------------------------------------------------------------
// k_prep_a: normalized codebook records (one thread per record), summed out
// bias, zero loss accumulator. 18 blocks x 256.
// ---------------------------------------------------------------------------
__global__ __launch_bounds__(256) void k_prep_a(
    const float* __restrict__ out_b, const float* __restrict__ cb,
    float* __restrict__ ws)
{
    int t = blockIdx.x * 256 + threadIdx.x;
    if (t == 0) ws[WS_LOSS] = 0.f;

    if (t < NS * K) {
        const float* c = cb + (long long)t * 8;
        float cv[8];
#pragma unroll
        for (int k = 0; k < 8; k++) cv[k] = c[k];
        float n2 = 0.f;
#pragma unroll
        for (int k = 0; k < 8; k++) n2 += cv[k] * cv[k];
        float den = fmaxf(sqrtf(n2), 1e-12f);
        float cn[8];
#pragma unroll
        for (int k = 0; k < 8; k++) cn[k] = cv[k] / den;
        float cn2 = 0.f;
#pragma unroll
        for (int k = 0; k < 8; k++) cn2 += cn[k] * cn[k];
        float* r = ws + WS_CBREC + (long long)t * 12;
#pragma unroll
        for (int k = 0; k < 8; k++) r[k] = -2.0f * cn[k];   // exact *2
        r[8] = cn2; r[9] = 0.f; r[10] = 0.f; r[11] = 0.f;
    } else if (t < NS * K + D) {
        int d = t - NS * K;
        ws[WS_OBS + d] = out_b[d] + out_b[512 + d] + out_b[1024 + d] + out_b[1536 + d];
    }
}

// ---------------------------------------------------------------------------
// k_prep_b: correction terms M_ij (8x8) and v_ij (8) in f64. One wave per
// output scalar (432 waves); lane-strided partials + shuffle reduce.
// pairs p: (i,j) = (1,0),(2,0),(2,1),(3,0),(3,1),(3,2)
// ---------------------------------------------------------------------------
__global__ __launch_bounds__(256) void k_prep_b(
    const float* __restrict__ in_w, const float* __restrict__ out_w,
    const float* __restrict__ out_b, float* __restrict__ ws)
{
    int gw = blockIdx.x * 4 + (threadIdx.x >> 6);
    int lane = threadIdx.x & 63;
    if (gw >= 6 * 72) return;
    int p = gw / 72, idx = gw % 72;
    int i, j;
    if (p == 0) { i = 1; j = 0; }
    else if (p < 3) { i = 2; j = p - 1; }
    else { i = 3; j = p - 3; }

    double acc = 0.0;
    if (idx < 64) {
        int ci = idx >> 3, cc = idx & 7;
        const float* wi = in_w + (long long)(i * 8 + ci) * 512;
        const float* wo = out_w + (long long)j * 4096;      // [d][8]
#pragma unroll
        for (int k = 0; k < 8; k++) {
            int d = lane + k * 64;
            acc += (double)wi[d] * (double)wo[d * 8 + cc];
        }
    } else {
        int ci = idx - 64;
        const float* wi = in_w + (long long)(i * 8 + ci) * 512;
        const float* bo = out_b + (long long)j * 512;
#pragma unroll
        for (int k = 0; k < 8; k++) {
            int d = lane + k * 64;
            acc += (double)wi[d] * (double)bo[d];
        }
    }
#pragma unroll
    for (int off = 32; off >= 1; off >>= 1) acc += __shfl_down(acc, off);
    if (lane == 0) ((double*)(ws + WS_CORR))[p * 72 + idx] = acc;
}

// ---------------------------------------------------------------------------
// k_pool_proj: one pass over z. Block = (b, 256-t span), 512 thr = 8 dsegs x
// 64 lanes (each lane owns 4 consecutive t). Hierarchical pooled projections
// for all 4 stages, LDS tree reduce over dsegs, write P0..P3 (+bias).
// ---------------------------------------------------------------------------
__global__ __launch_bounds__(512) void k_pool_proj(
    const float* __restrict__ z, const float* __restrict__ in_w,
    const float* __restrict__ in_b, float* __restrict__ ws)
{
    __shared__ float red[8][32][64];   // 64 KB
    int tid = threadIdx.x;
    int lane = tid & 63;
    int wv = __builtin_amdgcn_readfirstlane(tid >> 6);   // dseg, wave-uniform
    int b = blockIdx.x;
    int t0 = blockIdx.y * 256;

    const float* zrow = z + ((long long)b * D) * T + t0 + lane * 4;

    float a3[4][8] = {}; // stage3 (stride1), per-position
    float a2[2][8] = {}; // stage2 (stride2)
    float a1[8]    = {}; // stage1 (stride4)
    float a0[8]    = {}; // stage0 (stride8), partial (pairs of lanes combine)

    for (int dd = 0; dd < 64; dd++) {
        int d = wv * 64 + dd;
        float4 v = *(const float4*)(zrow + (long long)d * T);
        float s2a = v.x + v.y, s2b = v.z + v.w;
        float s4 = s2a + s2b;
#pragma unroll
        for (int c = 0; c < 8; c++) {
            float w3 = in_w[(3 * 8 + c) * 512 + d];
            float w2 = in_w[(2 * 8 + c) * 512 + d];
            float w1 = in_w[(1 * 8 + c) * 512 + d];
            float w0 = in_w[(0 * 8 + c) * 512 + d];
            a3[0][c] = fmaf(w3, v.x, a3[0][c]);
            a3[1][c] = fmaf(w3, v.y, a3[1][c]);
            a3[2][c] = fmaf(w3, v.z, a3[2][c]);
            a3[3][c] = fmaf(w3, v.w, a3[3][c]);
            a2[0][c] = fmaf(w2, s2a, a2[0][c]);
            a2[1][c] = fmaf(w2, s2b, a2[1][c]);
            a1[c]    = fmaf(w1, s4, a1[c]);
            a0[c]    = fmaf(w0, s4, a0[c]);
        }
    }

    // round 1: stage3 (32 slots)
#pragma unroll
    for (int pos = 0; pos < 4; pos++)
#pragma unroll
        for (int c = 0; c < 8; c++)
            red[wv][pos * 8 + c][lane] = a3[pos][c];
    __syncthreads();
    for (int o = tid; o < 2048; o += 512) {
        int ln = o & 63, s = o >> 6;
        float sum = 0.f;
#pragma unroll
        for (int w = 0; w < 8; w++) sum += red[w][s][ln];
        int pos = s >> 3, c = s & 7;
        int tp = t0 + ln * 4 + pos;
        ws[WS_P3 + ((long long)b * 4096 + tp) * 8 + c] = sum + in_b[3 * 8 + c];
    }
    __syncthreads();

    // round 2: stage2 (16 slots), stage1 (8), stage0 (8)
#pragma unroll
    for (int pos = 0; pos < 2; pos++)
#pragma unroll
        for (int c = 0; c < 8; c++)
            red[wv][pos * 8 + c][lane] = a2[pos][c];
#pragma unroll
    for (int c = 0; c < 8; c++) {
        red[wv][16 + c][lane] = a1[c];
        red[wv][24 + c][lane] = a0[c];
    }
    __syncthreads();
    for (int o = tid; o < 2048; o += 512) {
        int ln = o & 63, s = o >> 6;
        if (s < 16) {
            float sum = 0.f;
#pragma unroll
            for (int w = 0; w < 8; w++) sum += red[w][s][ln];
            int pos = s >> 3, c = s & 7;
            int tp = (t0 >> 1) + ln * 2 + pos;
            ws[WS_P2 + ((long long)b * 2048 + tp) * 8 + c] = sum * 0.5f + in_b[2 * 8 + c];
        } else if (s < 24) {
            int c = s - 16;
            float sum = 0.f;
#pragma unroll
            for (int w = 0; w < 8; w++) sum += red[w][s][ln];
            int tp = (t0 >> 2) + ln;
            ws[WS_P1 + ((long long)b * 1024 + tp) * 8 + c] = sum * 0.25f + in_b[8 + c];
        } else {
            if (ln & 1) continue;
            int c = s - 24;
            float sum = 0.f;
#pragma unroll
            for (int w = 0; w < 8; w++) sum += red[w][s][ln] + red[w][s][ln + 1];
            int tp = (t0 >> 3) + (ln >> 1);
            ws[WS_P0 + ((long long)b * 512 + tp) * 8 + c] = sum * 0.125f + in_b[c];
        }
    }
}

// ---------------------------------------------------------------------------
// k_vq<STAGE>: block = 64 vectors x 4 code-chunk waves. e from P minus f64
// corrections, normalize, argmin over 1024 codes (first-index tie rule),
// write q/codes/latents, accumulate loss.
// ---------------------------------------------------------------------------
template <int STAGE>
__global__ __launch_bounds__(256) void k_vq(
    const float* __restrict__ cb, float* __restrict__ ws, float* __restrict__ out)
{
    constexpr int TS = 512 << STAGE;
    constexpr long long PBASE = (STAGE == 0) ? WS_P0 : (STAGE == 1) ? WS_P1 : (STAGE == 2) ? WS_P2 : WS_P3;
    constexpr long long QBASE = (STAGE == 0) ? WS_Q0 : (STAGE == 1) ? WS_Q1 : (STAGE == 2) ? WS_Q2 : WS_Q3;

    int tid = threadIdx.x;
    int lane = tid & 63;
    int w = __builtin_amdgcn_readfirstlane(tid >> 6);

    long long v = (long long)blockIdx.x * 64 + lane;
    int b = (int)(v >> (9 + STAGE));
    int tp = (int)(v & (TS - 1));

    float e[8];
    const float* P = ws + PBASE + v * 8;
#pragma unroll
    for (int c = 0; c < 8; c++) e[c] = P[c];

    if (STAGE > 0) {
        double ed[8];
#pragma unroll
        for (int c = 0; c < 8; c++) ed[c] = (double)e[c];
        const double* corr = (const double*)(ws + WS_CORR);
        constexpr int pbase = (STAGE == 1) ? 0 : (STAGE == 2) ? 1 : 3;
#pragma unroll
        for (int j = 0; j < STAGE; j++) {
            const double* M = corr + (pbase + j) * 72;
            long long qb = (j == 0) ? WS_Q0 : (j == 1) ? WS_Q1 : WS_Q2;
            int tj = tp >> (STAGE - j);
            long long vj = ((long long)b << (9 + j)) + tj;
            const float* ql = ws + qb + vj * 8;
#pragma unroll
            for (int c = 0; c < 8; c++) {
                double acc = M[64 + c];
#pragma unroll
                for (int cc = 0; cc < 8; cc++) acc += M[c * 8 + cc] * (double)ql[cc];
                ed[c] -= acc;
            }
        }
#pragma unroll
        for (int c = 0; c < 8; c++) e[c] = (float)ed[c];
    }

    // normalize (F.normalize semantics: x / max(||x||, 1e-12))
    float n2 = 0.f;
#pragma unroll
    for (int c = 0; c < 8; c++) n2 = fmaf(e[c], e[c], n2);
    float den = fmaxf(sqrtf(n2), 1e-12f);
    float inv = 1.0f / den;
    float en[8];
#pragma unroll
    for (int c = 0; c < 8; c++) en[c] = e[c] * inv;
    float en2 = 0.f;
#pragma unroll
    for (int c = 0; c < 8; c++) en2 = fmaf(en[c], en[c], en2);

    // search this wave's 256-code chunk; uniform (scalar) code stream
    const float* rec = ws + WS_CBREC + (long long)STAGE * K * 12 + (long long)w * 256 * 12;
    float best = 3.0e38f;
    int bidx = 0;
    for (int jt = 0; jt < 256; jt++) {
        const float* r = rec + jt * 12;
        float acc = en2;
#pragma unroll
        for (int c = 0; c < 8; c++) acc = fmaf(r[c], en[c], acc);  // en2 - 2*dot
        float dist = acc + r[8];                                   // + cn2
        if (dist < best) { best = dist; bidx = w * 256 + jt; }
    }

    __shared__ float sb[4][64];
    __shared__ int si[4][64];
    sb[w][lane] = best;
    si[w][lane] = bidx;
    __syncthreads();

    if (tid < 64) {
        float bd = sb[0][lane];
        int bj = si[0][lane];
#pragma unroll
        for (int ww = 1; ww < 4; ww++) {
            float d2 = sb[ww][lane];
            int j2 = si[ww][lane];
            if (d2 < bd || (d2 == bd && j2 < bj)) { bd = d2; bj = j2; }
        }
        // unnormalized codebook lookup
        const float* qc = cb + ((long long)STAGE * K + bj) * 8;
        float qv[8];
#pragma unroll
        for (int c = 0; c < 8; c++) qv[c] = qc[c];
        float* qo = ws + QBASE + v * 8;
#pragma unroll
        for (int c = 0; c < 8; c++) qo[c] = qv[c];

        constexpr long long CODE_OFF = OUT_CODES0 + ((STAGE >= 1) ? 8192 : 0)
                                       + ((STAGE >= 2) ? 16384 : 0) + ((STAGE >= 3) ? 32768 : 0);
        out[CODE_OFF + v] = (float)bj;

        // commit/cb loss (identical values): mean over (c,t), then batch
        float l = 0.f;
#pragma unroll
        for (int c = 0; c < 8; c++) { float dq = e[c] - qv[c]; l = fmaf(dq, dq, l); }
#pragma unroll
        for (int off = 32; off >= 1; off >>= 1) l += __shfl_down(l, off);
        if (lane == 0) atomicAdd(ws + WS_LOSS, l * (1.0f / (8.0f * (float)TS * (float)B)));

        // latents: z_e repeated to full T
        constexpr int S = 8 >> STAGE;
        long long lat = OUT_LAT + ((long long)b * 32 + STAGE * 8) * T + (long long)tp * S;
#pragma unroll
        for (int c = 0; c < 8; c++)
            for (int k = 0; k < S; k++)
                out[lat + (long long)c * T + k] = e[c];
    }
}

// ---------------------------------------------------------------------------
// k_zq: z_q[b,d,t] = sum_i (ow_i q_i[t>>k_i]) + sum_i ob_i. Hierarchical
// (15 FMA/elem). Wave = (16-d group, 64 t1-blocks); lane stores 8 t as 2xfloat4.
// ---------------------------------------------------------------------------
__global__ __launch_bounds__(256) void k_zq(
    const float* __restrict__ out_w, const float* __restrict__ ws, float* __restrict__ out)
{
    int tid = threadIdx.x;
    int lane = tid & 63;
    int w = __builtin_amdgcn_readfirstlane(tid >> 6);
    int gw = blockIdx.x * 4 + w;           // 4096 waves
    int dgrp = gw & 31;                    // 16 d each
    int t1g = gw >> 5;                     // 128 chunks of 64 t1-blocks
    int t1 = t1g * 64 + lane;              // global t1-block id (0..8191)
    int b = t1 >> 9;
    int t1l = t1 & 511;

    float q0[8], q1a[2][8], q2a[4][8], q3a[8][8];
    {
        const float* Q = ws + WS_Q0 + ((long long)b * 512 + t1l) * 8;
#pragma unroll
        for (int c = 0; c < 8; c++) q0[c] = Q[c];
    }
    {
        const float* Q = ws + WS_Q1 + ((long long)b * 1024 + t1l * 2) * 8;
#pragma unroll
        for (int j = 0; j < 2; j++)
#pragma unroll
            for (int c = 0; c < 8; c++) q1a[j][c] = Q[j * 8 + c];
    }
    {
        const float* Q = ws + WS_Q2 + ((long long)b * 2048 + t1l * 4) * 8;
#pragma unroll
        for (int j = 0; j < 4; j++)
#pragma unroll
            for (int c = 0; c < 8; c++) q2a[j][c] = Q[j * 8 + c];
    }
    {
        const float* Q = ws + WS_Q3 + ((long long)b * 4096 + t1l * 8) * 8;
#pragma unroll
        for (int j = 0; j < 8; j++)
#pragma unroll
            for (int c = 0; c < 8; c++) q3a[j][c] = Q[j * 8 + c];
    }

    for (int dl = 0; dl < 16; dl++) {
        int d = dgrp * 16 + dl;
        const float* w0 = out_w + 0 * 4096 + d * 8;
        const float* w1 = out_w + 1 * 4096 + d * 8;
        const float* w2 = out_w + 2 * 4096 + d * 8;
        const float* w3 = out_w + 3 * 4096 + d * 8;
        float base0 = ws[WS_OBS + d];
#pragma unroll
        for (int c = 0; c < 8; c++) base0 = fmaf(w0[c], q0[c], base0);
        float res[8];
#pragma unroll
        for (int j1 = 0; j1 < 2; j1++) {
            float b1 = base0;
#pragma unroll
            for (int c = 0; c < 8; c++) b1 = fmaf(w1[c], q1a[j1][c], b1);
#pragma unroll
            for (int j2 = 0; j2 < 2; j2++) {
                float b2 = b1;
#pragma unroll
                for (int c = 0; c < 8; c++) b2 = fmaf(w2[c], q2a[j1 * 2 + j2][c], b2);
#pragma unroll
                for (int j3 = 0; j3 < 2; j3++) {
                    int tl = j1 * 4 + j2 * 2 + j3;
                    float b3 = b2;
#pragma unroll
                    for (int c = 0; c < 8; c++) b3 = fmaf(w3[c], q3a[tl][c], b3);
                    res[tl] = b3;
                }
            }
        }
        float* o = out + OUT_ZQ + ((long long)b * 512 + d) * T + (long long)t1l * 8;
        *(float4*)(o)     = make_float4(res[0], res[1], res[2], res[3]);
        *(float4*)(o + 4) = make_float4(res[4], res[5], res[6], res[7]);
    }

    if (blockIdx.x == 0 && tid == 0) {
        float L = ws[WS_LOSS];
        out[OUT_COMMIT] = L;
        out[OUT_CBL]    = L;   // identical by construction
    }
}

// ---------------------------------------------------------------------------
extern "C" void kernel_launch(void* const* d_in, const int* in_sizes, int n_in,
                              void* d_out, int out_size, void* d_ws, size_t ws_size,
                              hipStream_t stream)
{
    const float* z     = (const float*)d_in[0];
    const float* in_w  = (const float*)d_in[1];
    const float* in_b  = (const float*)d_in[2];
    const float* out_w = (const float*)d_in[3];
    const float* out_b = (const float*)d_in[4];
    const float* cb    = (const float*)d_in[5];
    float* out = (float*)d_out;
    float* ws  = (float*)d_ws;

    k_prep_a<<<dim3(18), dim3(256), 0, stream>>>(out_b, cb, ws);
    k_prep_b<<<dim3(108), dim3(256), 0, stream>>>(in_w, out_w, out_b, ws);
    k_pool_proj<<<dim3(16, 16), dim3(512), 0, stream>>>(z, in_w, in_b, ws);
    k_vq<0><<<dim3(8192 / 64), dim3(256), 0, stream>>>(cb, ws, out);
    k_vq<1><<<dim3(16384 / 64), dim3(256), 0, stream>>>(cb, ws, out);
    k_vq<2><<<dim3(32768 / 64), dim3(256), 0, stream>>>(cb, ws, out);
    k_vq<3><<<dim3(65536 / 64), dim3(256), 0, stream>>>(cb, ws, out);
    k_zq<<<dim3(1024), dim3(256), 0, stream>>>(out_w, ws, out);
}

// Round 3
// 247.242 us; speedup vs baseline: 1.6137x; 1.3187x over previous
//
#include <hip/hip_runtime.h>

// ---------------------------------------------------------------------------
// MultiScaleResidualVectorQuantize: 4-stage residual VQ, strides (8,4,2,1)
// Algebraic restructure: e_i = P_i - sum_{j<i} (M_ij q_j + v_ij) with
// P_i = iw_i * pool_i(z) + ib_i,  M_ij = iw_i*ow_j (8x8),  v_ij = iw_i*ob_j.
// One read of z, one write of z_q; cascade entirely in C=8 space.
// ---------------------------------------------------------------------------

constexpr int B = 16, D = 512, T = 4096, C = 8, K = 1024, NS = 4;

// output offsets (floats, concatenated in reference return order)
constexpr long long OUT_ZQ     = 0;                       // 16*512*4096
constexpr long long OUT_LAT    = 33554432LL;              // 16*32*4096
constexpr long long OUT_COMMIT = OUT_LAT + 2097152LL;     // 35651584
constexpr long long OUT_CBL    = OUT_COMMIT + 1;          // 35651585
constexpr long long OUT_CODES0 = OUT_CBL + 1;             // 35651586

// workspace offsets (floats)
constexpr long long WS_CBREC = 0;                 // 4*1024*12
constexpr long long WS_OBS   = 49152;             // 512 (sum of out biases)
constexpr long long WS_LOSS  = 49664;             // 1
constexpr long long WS_CORR  = 49696;             // doubles: 6 pairs * 72
constexpr long long WS_P0    = 52224;             // 8192*8
constexpr long long WS_P1    = WS_P0 + 65536;
constexpr long long WS_P2    = WS_P1 + 131072;
constexpr long long WS_P3    = WS_P2 + 262144;
constexpr long long WS_Q0    = WS_P3 + 524288;
constexpr long long WS_Q1    = WS_Q0 + 65536;
constexpr long long WS_Q2    = WS_Q1 + 131072;
constexpr long long WS_Q3    = WS_Q2 + 262144;    // ends ~8.1 MB

// ---------------------------------------------------------------------------
// k_prep_a: normalized codebook records (one thread per record), summed out
// bias, zero loss accumulator.
// ---------------------------------------------------------------------------
__global__ __launch_bounds__(256) void k_prep_a(
    const float* __restrict__ out_b, const float* __restrict__ cb,
    float* __restrict__ ws)
{
    int t = blockIdx.x * 256 + threadIdx.x;
    if (t == 0) ws[WS_LOSS] = 0.f;

    if (t < NS * K) {
        const float* c = cb + (long long)t * 8;
        float cv[8];
#pragma unroll
        for (int k = 0; k < 8; k++) cv[k] = c[k];
        float n2 = 0.f;
#pragma unroll
        for (int k = 0; k < 8; k++) n2 += cv[k] * cv[k];
        float den = fmaxf(sqrtf(n2), 1e-12f);
        float cn[8];
#pragma unroll
        for (int k = 0; k < 8; k++) cn[k] = cv[k] / den;
        float cn2 = 0.f;
#pragma unroll
        for (int k = 0; k < 8; k++) cn2 += cn[k] * cn[k];
        float* r = ws + WS_CBREC + (long long)t * 12;
#pragma unroll
        for (int k = 0; k < 8; k++) r[k] = -2.0f * cn[k];
        r[8] = cn2; r[9] = 0.f; r[10] = 0.f; r[11] = 0.f;
    } else if (t < NS * K + D) {
        int d = t - NS * K;
        ws[WS_OBS + d] = out_b[d] + out_b[512 + d] + out_b[1024 + d] + out_b[1536 + d];
    }
}

// ---------------------------------------------------------------------------
// k_prep_b: correction terms M_ij (8x8) and v_ij (8) in f64. One wave per
// output scalar (432 waves); lane-strided partials + shuffle reduce.
// ---------------------------------------------------------------------------
__global__ __launch_bounds__(256) void k_prep_b(
    const float* __restrict__ in_w, const float* __restrict__ out_w,
    const float* __restrict__ out_b, float* __restrict__ ws)
{
    int gw = blockIdx.x * 4 + (threadIdx.x >> 6);
    int lane = threadIdx.x & 63;
    if (gw >= 6 * 72) return;
    int p = gw / 72, idx = gw % 72;
    int i, j;
    if (p == 0) { i = 1; j = 0; }
    else if (p < 3) { i = 2; j = p - 1; }
    else { i = 3; j = p - 3; }

    double acc = 0.0;
    if (idx < 64) {
        int ci = idx >> 3, cc = idx & 7;
        const float* wi = in_w + (long long)(i * 8 + ci) * 512;
        const float* wo = out_w + (long long)j * 4096;      // [d][8]
#pragma unroll
        for (int k = 0; k < 8; k++) {
            int d = lane + k * 64;
            acc += (double)wi[d] * (double)wo[d * 8 + cc];
        }
    } else {
        int ci = idx - 64;
        const float* wi = in_w + (long long)(i * 8 + ci) * 512;
        const float* bo = out_b + (long long)j * 512;
#pragma unroll
        for (int k = 0; k < 8; k++) {
            int d = lane + k * 64;
            acc += (double)wi[d] * (double)bo[d];
        }
    }
#pragma unroll
    for (int off = 32; off >= 1; off >>= 1) acc += __shfl_down(acc, off);
    if (lane == 0) ((double*)(ws + WS_CORR))[p * 72 + idx] = acc;
}

// ---------------------------------------------------------------------------
// k_pool_proj v2: one pass over z. Block = (b, 256-t span), 512 thr = 8 dsegs
// x 64 lanes (lane owns 4 consecutive t). in_w staged once in LDS transposed
// ([d][36], padded) -> inner loop reads w as uniform ds_read_b128 broadcasts
// instead of 32 serialized scalar loads per iteration.
// ---------------------------------------------------------------------------
__global__ __launch_bounds__(512) void k_pool_proj(
    const float* __restrict__ z, const float* __restrict__ in_w,
    const float* __restrict__ in_b, float* __restrict__ ws)
{
    __shared__ float red[8][32][64];     // 64 KB (reduction tree)
    __shared__ float inwT[512 * 36];     // 72 KB ([d][36]: sc=s*8+c at [d*36+sc])

    int tid = threadIdx.x;
    int lane = tid & 63;
    int wv = __builtin_amdgcn_readfirstlane(tid >> 6);   // dseg, wave-uniform
    int b = blockIdx.x;
    int t0 = blockIdx.y * 256;

    // stage in_w -> LDS transposed (global reads coalesced per sc row)
#pragma unroll
    for (int sc = 0; sc < 32; ++sc)
        inwT[tid * 36 + sc] = in_w[sc * 512 + tid];
    __syncthreads();

    const float* zrow = z + ((long long)b * D) * T + t0 + lane * 4;

    float a3[4][8] = {}; // stage3 (stride1), per-position
    float a2[2][8] = {}; // stage2 (stride2)
    float a1[8]    = {}; // stage1 (stride4)
    float a0[8]    = {}; // stage0 (stride8), partial (pairs of lanes combine)

#pragma unroll 2
    for (int dd = 0; dd < 64; dd++) {
        int d = wv * 64 + dd;
        float4 v = *(const float4*)(zrow + (long long)d * T);
        const float* wrow = inwT + d * 36;
        float w0[8], w1[8], w2[8], w3[8];
        *(float4*)&w0[0] = *(const float4*)(wrow + 0);
        *(float4*)&w0[4] = *(const float4*)(wrow + 4);
        *(float4*)&w1[0] = *(const float4*)(wrow + 8);
        *(float4*)&w1[4] = *(const float4*)(wrow + 12);
        *(float4*)&w2[0] = *(const float4*)(wrow + 16);
        *(float4*)&w2[4] = *(const float4*)(wrow + 20);
        *(float4*)&w3[0] = *(const float4*)(wrow + 24);
        *(float4*)&w3[4] = *(const float4*)(wrow + 28);

        float s2a = v.x + v.y, s2b = v.z + v.w;
        float s4 = s2a + s2b;
#pragma unroll
        for (int c = 0; c < 8; c++) {
            a3[0][c] = fmaf(w3[c], v.x, a3[0][c]);
            a3[1][c] = fmaf(w3[c], v.y, a3[1][c]);
            a3[2][c] = fmaf(w3[c], v.z, a3[2][c]);
            a3[3][c] = fmaf(w3[c], v.w, a3[3][c]);
            a2[0][c] = fmaf(w2[c], s2a, a2[0][c]);
            a2[1][c] = fmaf(w2[c], s2b, a2[1][c]);
            a1[c]    = fmaf(w1[c], s4, a1[c]);
            a0[c]    = fmaf(w0[c], s4, a0[c]);
        }
    }

    __syncthreads();   // all waves done reading inwT before red overlaps usage patterns

    // round 1: stage3 (32 slots)
#pragma unroll
    for (int pos = 0; pos < 4; pos++)
#pragma unroll
        for (int c = 0; c < 8; c++)
            red[wv][pos * 8 + c][lane] = a3[pos][c];
    __syncthreads();
    for (int o = tid; o < 2048; o += 512) {
        int ln = o & 63, s = o >> 6;
        float sum = 0.f;
#pragma unroll
        for (int w = 0; w < 8; w++) sum += red[w][s][ln];
        int pos = s >> 3, c = s & 7;
        int tp = t0 + ln * 4 + pos;
        ws[WS_P3 + ((long long)b * 4096 + tp) * 8 + c] = sum + in_b[3 * 8 + c];
    }
    __syncthreads();

    // round 2: stage2 (16 slots), stage1 (8), stage0 (8)
#pragma unroll
    for (int pos = 0; pos < 2; pos++)
#pragma unroll
        for (int c = 0; c < 8; c++)
            red[wv][pos * 8 + c][lane] = a2[pos][c];
#pragma unroll
    for (int c = 0; c < 8; c++) {
        red[wv][16 + c][lane] = a1[c];
        red[wv][24 + c][lane] = a0[c];
    }
    __syncthreads();
    for (int o = tid; o < 2048; o += 512) {
        int ln = o & 63, s = o >> 6;
        if (s < 16) {
            float sum = 0.f;
#pragma unroll
            for (int w = 0; w < 8; w++) sum += red[w][s][ln];
            int pos = s >> 3, c = s & 7;
            int tp = (t0 >> 1) + ln * 2 + pos;
            ws[WS_P2 + ((long long)b * 2048 + tp) * 8 + c] = sum * 0.5f + in_b[2 * 8 + c];
        } else if (s < 24) {
            int c = s - 16;
            float sum = 0.f;
#pragma unroll
            for (int w = 0; w < 8; w++) sum += red[w][s][ln];
            int tp = (t0 >> 2) + ln;
            ws[WS_P1 + ((long long)b * 1024 + tp) * 8 + c] = sum * 0.25f + in_b[8 + c];
        } else {
            if (ln & 1) continue;
            int c = s - 24;
            float sum = 0.f;
#pragma unroll
            for (int w = 0; w < 8; w++) sum += red[w][s][ln] + red[w][s][ln + 1];
            int tp = (t0 >> 3) + (ln >> 1);
            ws[WS_P0 + ((long long)b * 512 + tp) * 8 + c] = sum * 0.125f + in_b[c];
        }
    }
}

// ---------------------------------------------------------------------------
// k_vq<STAGE>: block = 64 vectors x 4 code-chunk waves. e from P minus f64
// corrections, normalize, argmin over 1024 codes (first-index tie rule),
// write q/codes/latents, accumulate loss.
// ---------------------------------------------------------------------------
template <int STAGE>
__global__ __launch_bounds__(256) void k_vq(
    const float* __restrict__ cb, float* __restrict__ ws, float* __restrict__ out)
{
    constexpr int TS = 512 << STAGE;
    constexpr long long PBASE = (STAGE == 0) ? WS_P0 : (STAGE == 1) ? WS_P1 : (STAGE == 2) ? WS_P2 : WS_P3;
    constexpr long long QBASE = (STAGE == 0) ? WS_Q0 : (STAGE == 1) ? WS_Q1 : (STAGE == 2) ? WS_Q2 : WS_Q3;

    int tid = threadIdx.x;
    int lane = tid & 63;
    int w = __builtin_amdgcn_readfirstlane(tid >> 6);

    long long v = (long long)blockIdx.x * 64 + lane;
    int b = (int)(v >> (9 + STAGE));
    int tp = (int)(v & (TS - 1));

    float e[8];
    const float* P = ws + PBASE + v * 8;
#pragma unroll
    for (int c = 0; c < 8; c++) e[c] = P[c];

    if (STAGE > 0) {
        double ed[8];
#pragma unroll
        for (int c = 0; c < 8; c++) ed[c] = (double)e[c];
        const double* corr = (const double*)(ws + WS_CORR);
        constexpr int pbase = (STAGE == 1) ? 0 : (STAGE == 2) ? 1 : 3;
#pragma unroll
        for (int j = 0; j < STAGE; j++) {
            const double* M = corr + (pbase + j) * 72;
            long long qb = (j == 0) ? WS_Q0 : (j == 1) ? WS_Q1 : WS_Q2;
            int tj = tp >> (STAGE - j);
            long long vj = ((long long)b << (9 + j)) + tj;
            const float* ql = ws + qb + vj * 8;
#pragma unroll
            for (int c = 0; c < 8; c++) {
                double acc = M[64 + c];
#pragma unroll
                for (int cc = 0; cc < 8; cc++) acc += M[c * 8 + cc] * (double)ql[cc];
                ed[c] -= acc;
            }
        }
#pragma unroll
        for (int c = 0; c < 8; c++) e[c] = (float)ed[c];
    }

    // normalize (F.normalize semantics: x / max(||x||, 1e-12))
    float n2 = 0.f;
#pragma unroll
    for (int c = 0; c < 8; c++) n2 = fmaf(e[c], e[c], n2);
    float den = fmaxf(sqrtf(n2), 1e-12f);
    float inv = 1.0f / den;
    float en[8];
#pragma unroll
    for (int c = 0; c < 8; c++) en[c] = e[c] * inv;
    float en2 = 0.f;
#pragma unroll
    for (int c = 0; c < 8; c++) en2 = fmaf(en[c], en[c], en2);

    // search this wave's 256-code chunk; uniform (scalar) code stream
    const float* rec = ws + WS_CBREC + (long long)STAGE * K * 12 + (long long)w * 256 * 12;
    float best = 3.0e38f;
    int bidx = 0;
    for (int jt = 0; jt < 256; jt++) {
        const float* r = rec + jt * 12;
        float acc = en2;
#pragma unroll
        for (int c = 0; c < 8; c++) acc = fmaf(r[c], en[c], acc);  // en2 - 2*dot
        float dist = acc + r[8];                                   // + cn2
        if (dist < best) { best = dist; bidx = w * 256 + jt; }
    }

    __shared__ float sb[4][64];
    __shared__ int si[4][64];
    sb[w][lane] = best;
    si[w][lane] = bidx;
    __syncthreads();

    if (tid < 64) {
        float bd = sb[0][lane];
        int bj = si[0][lane];
#pragma unroll
        for (int ww = 1; ww < 4; ww++) {
            float d2 = sb[ww][lane];
            int j2 = si[ww][lane];
            if (d2 < bd || (d2 == bd && j2 < bj)) { bd = d2; bj = j2; }
        }
        // unnormalized codebook lookup
        const float* qc = cb + ((long long)STAGE * K + bj) * 8;
        float qv[8];
#pragma unroll
        for (int c = 0; c < 8; c++) qv[c] = qc[c];
        float* qo = ws + QBASE + v * 8;
#pragma unroll
        for (int c = 0; c < 8; c++) qo[c] = qv[c];

        constexpr long long CODE_OFF = OUT_CODES0 + ((STAGE >= 1) ? 8192 : 0)
                                       + ((STAGE >= 2) ? 16384 : 0) + ((STAGE >= 3) ? 32768 : 0);
        out[CODE_OFF + v] = (float)bj;

        // commit/cb loss (identical values): mean over (c,t), then batch
        float l = 0.f;
#pragma unroll
        for (int c = 0; c < 8; c++) { float dq = e[c] - qv[c]; l = fmaf(dq, dq, l); }
#pragma unroll
        for (int off = 32; off >= 1; off >>= 1) l += __shfl_down(l, off);
        if (lane == 0) atomicAdd(ws + WS_LOSS, l * (1.0f / (8.0f * (float)TS * (float)B)));

        // latents: z_e repeated to full T
        constexpr int S = 8 >> STAGE;
        long long lat = OUT_LAT + ((long long)b * 32 + STAGE * 8) * T + (long long)tp * S;
#pragma unroll
        for (int c = 0; c < 8; c++)
            for (int k = 0; k < S; k++)
                out[lat + (long long)c * T + k] = e[c];
    }
}

// ---------------------------------------------------------------------------
// k_zq v2: z_q[b,d,t] = sum_i dot8(ow_i[d], q_i[t>>k_i]) + obs[d].
// Lane owns 2 consecutive t (q-state = 40 floats); wave covers 128 t and
// iterates 8 d (uniform -> scalar w loads). 8192 blocks, low VGPR, deep
// store pipeline. Same per-element FMA order as v1 (bit-identical output).
// ---------------------------------------------------------------------------
__global__ __launch_bounds__(256) void k_zq(
    const float* __restrict__ out_w, const float* __restrict__ ws, float* __restrict__ out)
{
    int tid = threadIdx.x;
    int lane = tid & 63;
    int w = __builtin_amdgcn_readfirstlane(tid >> 6);
    int bid = blockIdx.x;                 // 8192 = 16 b * 64 dgrp * 8 tchunk
    int tc   = bid & 7;
    int g    = (bid >> 3) & 63;
    int b    = bid >> 9;
    int t    = tc * 512 + w * 128 + lane * 2;   // even

    float q0[8], q1[8], q2[8], q3a[8], q3b[8];
    {
        const float* Q = ws + WS_Q0 + ((long long)b * 512 + (t >> 3)) * 8;
#pragma unroll
        for (int c = 0; c < 8; c++) q0[c] = Q[c];
    }
    {
        const float* Q = ws + WS_Q1 + ((long long)b * 1024 + (t >> 2)) * 8;
#pragma unroll
        for (int c = 0; c < 8; c++) q1[c] = Q[c];
    }
    {
        const float* Q = ws + WS_Q2 + ((long long)b * 2048 + (t >> 1)) * 8;
#pragma unroll
        for (int c = 0; c < 8; c++) q2[c] = Q[c];
    }
    {
        const float* Q = ws + WS_Q3 + ((long long)b * 4096 + t) * 8;
#pragma unroll
        for (int c = 0; c < 8; c++) { q3a[c] = Q[c]; q3b[c] = Q[8 + c]; }
    }

#pragma unroll 2
    for (int dl = 0; dl < 8; dl++) {
        int d = g * 8 + dl;
        const float* w0 = out_w + 0 * 4096 + d * 8;
        const float* w1 = out_w + 1 * 4096 + d * 8;
        const float* w2 = out_w + 2 * 4096 + d * 8;
        const float* w3 = out_w + 3 * 4096 + d * 8;

        float acc = ws[WS_OBS + d];
#pragma unroll
        for (int c = 0; c < 8; c++) acc = fmaf(w0[c], q0[c], acc);
#pragma unroll
        for (int c = 0; c < 8; c++) acc = fmaf(w1[c], q1[c], acc);
#pragma unroll
        for (int c = 0; c < 8; c++) acc = fmaf(w2[c], q2[c], acc);
        float r0 = acc, r1 = acc;
#pragma unroll
        for (int c = 0; c < 8; c++) {
            r0 = fmaf(w3[c], q3a[c], r0);
            r1 = fmaf(w3[c], q3b[c], r1);
        }
        float* o = out + OUT_ZQ + ((long long)b * 512 + d) * T + t;
        *(float2*)o = make_float2(r0, r1);
    }

    if (bid == 0 && tid == 0) {
        float L = ws[WS_LOSS];
        out[OUT_COMMIT] = L;
        out[OUT_CBL]    = L;
    }
}

// ---------------------------------------------------------------------------
extern "C" void kernel_launch(void* const* d_in, const int* in_sizes, int n_in,
                              void* d_out, int out_size, void* d_ws, size_t ws_size,
                              hipStream_t stream)
{
    const float* z     = (const float*)d_in[0];
    const float* in_w  = (const float*)d_in[1];
    const float* in_b  = (const float*)d_in[2];
    const float* out_w = (const float*)d_in[3];
    const float* out_b = (const float*)d_in[4];
    const float* cb    = (const float*)d_in[5];
    float* out = (float*)d_out;
    float* ws  = (float*)d_ws;

    k_prep_a<<<dim3(18), dim3(256), 0, stream>>>(out_b, cb, ws);
    k_prep_b<<<dim3(108), dim3(256), 0, stream>>>(in_w, out_w, out_b, ws);
    k_pool_proj<<<dim3(16, 16), dim3(512), 0, stream>>>(z, in_w, in_b, ws);
    k_vq<0><<<dim3(8192 / 64), dim3(256), 0, stream>>>(cb, ws, out);
    k_vq<1><<<dim3(16384 / 64), dim3(256), 0, stream>>>(cb, ws, out);
    k_vq<2><<<dim3(32768 / 64), dim3(256), 0, stream>>>(cb, ws, out);
    k_vq<3><<<dim3(65536 / 64), dim3(256), 0, stream>>>(cb, ws, out);
    k_zq<<<dim3(8192), dim3(256), 0, stream>>>(out_w, ws, out);
}

// Round 4
// 195.896 us; speedup vs baseline: 2.0367x; 1.2621x over previous
//
#include <hip/hip_runtime.h>

// ---------------------------------------------------------------------------
// MultiScaleResidualVectorQuantize: 4-stage residual VQ, strides (8,4,2,1)
// Algebraic restructure: e_i = P_i - sum_{j<i} (M_ij q_j + v_ij) with
// P_i = iw_i * pool_i(z) + ib_i,  M_ij = iw_i*ow_j (8x8),  v_ij = iw_i*ob_j.
// One read of z, one write of z_q; cascade entirely in C=8 space.
// ---------------------------------------------------------------------------

constexpr int B = 16, D = 512, T = 4096, C = 8, K = 1024, NS = 4;

// output offsets (floats, concatenated in reference return order)
constexpr long long OUT_ZQ     = 0;                       // 16*512*4096
constexpr long long OUT_LAT    = 33554432LL;              // 16*32*4096
constexpr long long OUT_COMMIT = OUT_LAT + 2097152LL;     // 35651584
constexpr long long OUT_CBL    = OUT_COMMIT + 1;          // 35651585
constexpr long long OUT_CODES0 = OUT_CBL + 1;             // 35651586

// workspace offsets (floats)
constexpr long long WS_CBREC = 0;                 // 4*1024*12
constexpr long long WS_OBS   = 49152;             // 512 (sum of out biases)
constexpr long long WS_LOSS  = 49664;             // 1
constexpr long long WS_CORR  = 49696;             // doubles: 6 pairs * 72
constexpr long long WS_P0    = 52224;             // 8192*8
constexpr long long WS_P1    = WS_P0 + 65536;
constexpr long long WS_P2    = WS_P1 + 131072;
constexpr long long WS_P3    = WS_P2 + 262144;
constexpr long long WS_Q0    = WS_P3 + 524288;
constexpr long long WS_Q1    = WS_Q0 + 65536;
constexpr long long WS_Q2    = WS_Q1 + 131072;
constexpr long long WS_Q3    = WS_Q2 + 262144;    // ends ~8.1 MB

// ---------------------------------------------------------------------------
// k_prep (merged): blocks 0..17 -> codebook records + summed bias + loss=0;
// blocks 18..125 -> correction terms M_ij/v_ij in f64 (one wave per scalar).
// ---------------------------------------------------------------------------
__global__ __launch_bounds__(256) void k_prep(
    const float* __restrict__ in_w, const float* __restrict__ out_w,
    const float* __restrict__ out_b, const float* __restrict__ cb,
    float* __restrict__ ws)
{
    int bid = blockIdx.x;
    int tid = threadIdx.x;

    if (bid < 18) {
        int t = bid * 256 + tid;
        if (t == 0) ws[WS_LOSS] = 0.f;
        if (t < NS * K) {
            const float* c = cb + (long long)t * 8;
            float cv[8];
#pragma unroll
            for (int k = 0; k < 8; k++) cv[k] = c[k];
            float n2 = 0.f;
#pragma unroll
            for (int k = 0; k < 8; k++) n2 += cv[k] * cv[k];
            float den = fmaxf(sqrtf(n2), 1e-12f);
            float cn[8];
#pragma unroll
            for (int k = 0; k < 8; k++) cn[k] = cv[k] / den;
            float cn2 = 0.f;
#pragma unroll
            for (int k = 0; k < 8; k++) cn2 += cn[k] * cn[k];
            float* r = ws + WS_CBREC + (long long)t * 12;
#pragma unroll
            for (int k = 0; k < 8; k++) r[k] = -2.0f * cn[k];
            r[8] = cn2; r[9] = 0.f; r[10] = 0.f; r[11] = 0.f;
        } else if (t < NS * K + D) {
            int d = t - NS * K;
            ws[WS_OBS + d] = out_b[d] + out_b[512 + d] + out_b[1024 + d] + out_b[1536 + d];
        }
        return;
    }

    int gw = (bid - 18) * 4 + (tid >> 6);
    int lane = tid & 63;
    if (gw >= 6 * 72) return;
    int p = gw / 72, idx = gw % 72;
    int i, j;
    if (p == 0) { i = 1; j = 0; }
    else if (p < 3) { i = 2; j = p - 1; }
    else { i = 3; j = p - 3; }

    double acc = 0.0;
    if (idx < 64) {
        int ci = idx >> 3, cc = idx & 7;
        const float* wi = in_w + (long long)(i * 8 + ci) * 512;
        const float* wo = out_w + (long long)j * 4096;      // [d][8]
#pragma unroll
        for (int k = 0; k < 8; k++) {
            int d = lane + k * 64;
            acc += (double)wi[d] * (double)wo[d * 8 + cc];
        }
    } else {
        int ci = idx - 64;
        const float* wi = in_w + (long long)(i * 8 + ci) * 512;
        const float* bo = out_b + (long long)j * 512;
#pragma unroll
        for (int k = 0; k < 8; k++) {
            int d = lane + k * 64;
            acc += (double)wi[d] * (double)bo[d];
        }
    }
#pragma unroll
    for (int off = 32; off >= 1; off >>= 1) acc += __shfl_down(acc, off);
    if (lane == 0) ((double*)(ws + WS_CORR))[p * 72 + idx] = acc;
}

// ---------------------------------------------------------------------------
// k_pool_proj v3: block = (b, 128-t span), 512 thr = 8 dsegs x 64 lanes,
// lane owns 2 consecutive t (float2 load). in_w staged in LDS [d][36];
// reduction tree ALIASED into the same 72KB buffer (sync-separated) ->
// 72KB LDS total -> 2 blocks/CU, 4 waves/SIMD. Grid 16x32 = 512 blocks.
// ---------------------------------------------------------------------------
__global__ __launch_bounds__(512) void k_pool_proj(
    const float* __restrict__ z, const float* __restrict__ in_w,
    const float* __restrict__ in_b, float* __restrict__ ws)
{
    __shared__ float smem[512 * 36];     // 72 KB: in_w [d][36], later reduction tree

    int tid = threadIdx.x;
    int lane = tid & 63;
    int wv = __builtin_amdgcn_readfirstlane(tid >> 6);   // dseg, wave-uniform
    int b = blockIdx.x;
    int t0 = blockIdx.y * 128;

    // stage in_w -> LDS transposed
#pragma unroll
    for (int sc = 0; sc < 32; ++sc)
        smem[tid * 36 + sc] = in_w[sc * 512 + tid];
    __syncthreads();

    const float* zrow = z + ((long long)b * D) * T + t0 + lane * 2;

    float a3[2][8] = {}; // stage3 (stride1), per-position
    float a2[8]    = {}; // stage2 (stride2)
    float a1[8]    = {}; // stage1 partial (lane pairs combine)
    float a0[8]    = {}; // stage0 partial (4 lanes combine)

#pragma unroll 2
    for (int dd = 0; dd < 64; dd++) {
        int d = wv * 64 + dd;
        float2 v = *(const float2*)(zrow + (long long)d * T);
        const float* wrow = smem + d * 36;
        float w0[8], w1[8], w2[8], w3[8];
        *(float4*)&w0[0] = *(const float4*)(wrow + 0);
        *(float4*)&w0[4] = *(const float4*)(wrow + 4);
        *(float4*)&w1[0] = *(const float4*)(wrow + 8);
        *(float4*)&w1[4] = *(const float4*)(wrow + 12);
        *(float4*)&w2[0] = *(const float4*)(wrow + 16);
        *(float4*)&w2[4] = *(const float4*)(wrow + 20);
        *(float4*)&w3[0] = *(const float4*)(wrow + 24);
        *(float4*)&w3[4] = *(const float4*)(wrow + 28);

        float s2 = v.x + v.y;
#pragma unroll
        for (int c = 0; c < 8; c++) {
            a3[0][c] = fmaf(w3[c], v.x, a3[0][c]);
            a3[1][c] = fmaf(w3[c], v.y, a3[1][c]);
            a2[c]    = fmaf(w2[c], s2, a2[c]);
            a1[c]    = fmaf(w1[c], s2, a1[c]);
            a0[c]    = fmaf(w0[c], s2, a0[c]);
        }
    }

    __syncthreads();   // done reading in_w slice; smem now reused as tree

    // round 1: stage3, 16 slots/wave
    {
        float (*red)[16][64] = (float (*)[16][64])smem;
#pragma unroll
        for (int pos = 0; pos < 2; pos++)
#pragma unroll
            for (int c = 0; c < 8; c++)
                red[wv][pos * 8 + c][lane] = a3[pos][c];
        __syncthreads();
        for (int o = tid; o < 1024; o += 512) {
            int ln = o & 63, s = o >> 6;
            float sum = 0.f;
#pragma unroll
            for (int w = 0; w < 8; w++) sum += red[w][s][ln];
            int pos = s >> 3, c = s & 7;
            int tp = t0 + ln * 2 + pos;
            ws[WS_P3 + ((long long)b * 4096 + tp) * 8 + c] = sum + in_b[3 * 8 + c];
        }
        __syncthreads();
    }

    // round 2: stage2 (slots 0..7), stage1 partial (8..15), stage0 partial (16..23)
    {
        float (*red)[24][64] = (float (*)[24][64])smem;
#pragma unroll
        for (int c = 0; c < 8; c++) {
            red[wv][c][lane]      = a2[c];
            red[wv][8 + c][lane]  = a1[c];
            red[wv][16 + c][lane] = a0[c];
        }
        __syncthreads();
        for (int o = tid; o < 1536; o += 512) {
            int ln = o & 63, s = o >> 6;
            if (s < 8) {
                int c = s;
                float sum = 0.f;
#pragma unroll
                for (int w = 0; w < 8; w++) sum += red[w][s][ln];
                int tp = (t0 >> 1) + ln;
                ws[WS_P2 + ((long long)b * 2048 + tp) * 8 + c] = sum * 0.5f + in_b[2 * 8 + c];
            } else if (s < 16) {
                if (ln >= 32) continue;
                int c = s - 8;
                float sum = 0.f;
#pragma unroll
                for (int w = 0; w < 8; w++) sum += red[w][s][2 * ln] + red[w][s][2 * ln + 1];
                int tp = (t0 >> 2) + ln;
                ws[WS_P1 + ((long long)b * 1024 + tp) * 8 + c] = sum * 0.25f + in_b[8 + c];
            } else {
                if (ln >= 16) continue;
                int c = s - 16;
                float sum = 0.f;
#pragma unroll
                for (int w = 0; w < 8; w++)
#pragma unroll
                    for (int k = 0; k < 4; k++) sum += red[w][s][4 * ln + k];
                int tp = (t0 >> 3) + ln;
                ws[WS_P0 + ((long long)b * 512 + tp) * 8 + c] = sum * 0.125f + in_b[c];
            }
        }
    }
}

// ---------------------------------------------------------------------------
// k_vq<STAGE>: block = 64 vectors x 8 code-chunk waves (512 thr). e from P
// minus f64 corrections, normalize, argmin over 1024 codes (128/wave,
// first-index tie rule), write q/codes/loss; latents written cooperatively
// by all 512 threads (coalesced) from an e-broadcast LDS buffer.
// ---------------------------------------------------------------------------
template <int STAGE>
__global__ __launch_bounds__(512) void k_vq(
    const float* __restrict__ cb, float* __restrict__ ws, float* __restrict__ out)
{
    constexpr int TS = 512 << STAGE;
    constexpr long long PBASE = (STAGE == 0) ? WS_P0 : (STAGE == 1) ? WS_P1 : (STAGE == 2) ? WS_P2 : WS_P3;
    constexpr long long QBASE = (STAGE == 0) ? WS_Q0 : (STAGE == 1) ? WS_Q1 : (STAGE == 2) ? WS_Q2 : WS_Q3;

    int tid = threadIdx.x;
    int lane = tid & 63;
    int w = __builtin_amdgcn_readfirstlane(tid >> 6);   // 0..7

    long long v = (long long)blockIdx.x * 64 + lane;
    int b = (int)(v >> (9 + STAGE));
    int tp = (int)(v & (TS - 1));

    float e[8];
    const float* P = ws + PBASE + v * 8;
#pragma unroll
    for (int c = 0; c < 8; c++) e[c] = P[c];

    if (STAGE > 0) {
        double ed[8];
#pragma unroll
        for (int c = 0; c < 8; c++) ed[c] = (double)e[c];
        const double* corr = (const double*)(ws + WS_CORR);
        constexpr int pbase = (STAGE == 1) ? 0 : (STAGE == 2) ? 1 : 3;
#pragma unroll
        for (int j = 0; j < STAGE; j++) {
            const double* M = corr + (pbase + j) * 72;
            long long qb = (j == 0) ? WS_Q0 : (j == 1) ? WS_Q1 : WS_Q2;
            int tj = tp >> (STAGE - j);
            long long vj = ((long long)b << (9 + j)) + tj;
            const float* ql = ws + qb + vj * 8;
#pragma unroll
            for (int c = 0; c < 8; c++) {
                double acc = M[64 + c];
#pragma unroll
                for (int cc = 0; cc < 8; cc++) acc += M[c * 8 + cc] * (double)ql[cc];
                ed[c] -= acc;
            }
        }
#pragma unroll
        for (int c = 0; c < 8; c++) e[c] = (float)ed[c];
    }

    // normalize (F.normalize semantics: x / max(||x||, 1e-12))
    float n2 = 0.f;
#pragma unroll
    for (int c = 0; c < 8; c++) n2 = fmaf(e[c], e[c], n2);
    float den = fmaxf(sqrtf(n2), 1e-12f);
    float inv = 1.0f / den;
    float en[8];
#pragma unroll
    for (int c = 0; c < 8; c++) en[c] = e[c] * inv;
    float en2 = 0.f;
#pragma unroll
    for (int c = 0; c < 8; c++) en2 = fmaf(en[c], en[c], en2);

    // search this wave's 128-code chunk; wave-uniform code stream
    const float* rec = ws + WS_CBREC + (long long)STAGE * K * 12 + (long long)w * 128 * 12;
    float best = 3.0e38f;
    int bidx = 0;
    for (int jt = 0; jt < 128; jt++) {
        const float* r = rec + jt * 12;
        float acc = en2;
#pragma unroll
        for (int c = 0; c < 8; c++) acc = fmaf(r[c], en[c], acc);  // en2 - 2*dot
        float dist = acc + r[8];                                   // + cn2
        if (dist < best) { best = dist; bidx = w * 128 + jt; }
    }

    __shared__ float sb[8][64];
    __shared__ int si[8][64];
    __shared__ float e_lds[64][9];
    sb[w][lane] = best;
    si[w][lane] = bidx;
    if (w == 0) {
#pragma unroll
        for (int c = 0; c < 8; c++) e_lds[lane][c] = e[c];
    }
    __syncthreads();

    if (tid < 64) {
        float bd = sb[0][lane];
        int bj = si[0][lane];
#pragma unroll
        for (int ww = 1; ww < 8; ww++) {
            float d2 = sb[ww][lane];
            int j2 = si[ww][lane];
            if (d2 < bd || (d2 == bd && j2 < bj)) { bd = d2; bj = j2; }
        }
        // unnormalized codebook lookup
        const float* qc = cb + ((long long)STAGE * K + bj) * 8;
        float qv[8];
#pragma unroll
        for (int c = 0; c < 8; c++) qv[c] = qc[c];
        float* qo = ws + QBASE + v * 8;
#pragma unroll
        for (int c = 0; c < 8; c++) qo[c] = qv[c];

        constexpr long long CODE_OFF = OUT_CODES0 + ((STAGE >= 1) ? 8192 : 0)
                                       + ((STAGE >= 2) ? 16384 : 0) + ((STAGE >= 3) ? 32768 : 0);
        out[CODE_OFF + v] = (float)bj;

        // commit/cb loss (identical values): mean over (c,t), then batch
        float l = 0.f;
#pragma unroll
        for (int c = 0; c < 8; c++) { float dq = e[c] - qv[c]; l = fmaf(dq, dq, l); }
#pragma unroll
        for (int off = 32; off >= 1; off >>= 1) l += __shfl_down(l, off);
        if (lane == 0) atomicAdd(ws + WS_LOSS, l * (1.0f / (8.0f * (float)TS * (float)B)));
    }

    // cooperative latents write (all 512 threads, coalesced):
    // lat(v0+vl) + c*T + k = lat0 + c*T + vl*S + k
    constexpr int S = 8 >> STAGE;
    {
        long long v0 = (long long)blockIdx.x * 64;
        int b0 = (int)(v0 >> (9 + STAGE));
        int tp0 = (int)(v0 & (TS - 1));
        long long lat0 = OUT_LAT + ((long long)b0 * 32 + STAGE * 8) * T + (long long)tp0 * S;
        for (int o = tid; o < 64 * 8 * S; o += 512) {
            int c = o / (64 * S);
            int r = o - c * (64 * S);
            out[lat0 + (long long)c * T + r] = e_lds[r / S][c];
        }
    }
}

// ---------------------------------------------------------------------------
// k_zq v3: lane owns 4 consecutive t -> float4 stores; wave covers 256 t and
// 8 d (uniform scalar w loads). 4096 blocks. Same per-element FMA chain as
// v1/v2 (bit-identical z_q).
// ---------------------------------------------------------------------------
__global__ __launch_bounds__(256) void k_zq(
    const float* __restrict__ out_w, const float* __restrict__ ws, float* __restrict__ out)
{
    int tid = threadIdx.x;
    int lane = tid & 63;
    int w = __builtin_amdgcn_readfirstlane(tid >> 6);
    int bid = blockIdx.x;                 // 4096 = 16 b * 64 dgrp * 4 tchunk
    int tc   = bid & 3;
    int g    = (bid >> 2) & 63;
    int b    = bid >> 8;
    int t    = tc * 1024 + w * 256 + lane * 4;   // multiple of 4

    float q0[8], q1[8], q2[2][8], q3[4][8];
    {
        const float* Q = ws + WS_Q0 + ((long long)b * 512 + (t >> 3)) * 8;
#pragma unroll
        for (int c = 0; c < 8; c++) q0[c] = Q[c];
    }
    {
        const float* Q = ws + WS_Q1 + ((long long)b * 1024 + (t >> 2)) * 8;
#pragma unroll
        for (int c = 0; c < 8; c++) q1[c] = Q[c];
    }
    {
        const float* Q = ws + WS_Q2 + ((long long)b * 2048 + (t >> 1)) * 8;
#pragma unroll
        for (int j = 0; j < 2; j++)
#pragma unroll
            for (int c = 0; c < 8; c++) q2[j][c] = Q[j * 8 + c];
    }
    {
        const float* Q = ws + WS_Q3 + ((long long)b * 4096 + t) * 8;
#pragma unroll
        for (int j = 0; j < 4; j++)
#pragma unroll
            for (int c = 0; c < 8; c++) q3[j][c] = Q[j * 8 + c];
    }

#pragma unroll 2
    for (int dl = 0; dl < 8; dl++) {
        int d = g * 8 + dl;
        const float* w0 = out_w + 0 * 4096 + d * 8;
        const float* w1 = out_w + 1 * 4096 + d * 8;
        const float* w2 = out_w + 2 * 4096 + d * 8;
        const float* w3 = out_w + 3 * 4096 + d * 8;

        float acc = ws[WS_OBS + d];
#pragma unroll
        for (int c = 0; c < 8; c++) acc = fmaf(w0[c], q0[c], acc);
#pragma unroll
        for (int c = 0; c < 8; c++) acc = fmaf(w1[c], q1[c], acc);
        float accA = acc, accB = acc;
#pragma unroll
        for (int c = 0; c < 8; c++) {
            accA = fmaf(w2[c], q2[0][c], accA);
            accB = fmaf(w2[c], q2[1][c], accB);
        }
        float r0 = accA, r1 = accA, r2 = accB, r3 = accB;
#pragma unroll
        for (int c = 0; c < 8; c++) {
            r0 = fmaf(w3[c], q3[0][c], r0);
            r1 = fmaf(w3[c], q3[1][c], r1);
            r2 = fmaf(w3[c], q3[2][c], r2);
            r3 = fmaf(w3[c], q3[3][c], r3);
        }
        float* o = out + OUT_ZQ + ((long long)b * 512 + d) * T + t;
        *(float4*)o = make_float4(r0, r1, r2, r3);
    }

    if (bid == 0 && tid == 0) {
        float L = ws[WS_LOSS];
        out[OUT_COMMIT] = L;
        out[OUT_CBL]    = L;
    }
}

// ---------------------------------------------------------------------------
extern "C" void kernel_launch(void* const* d_in, const int* in_sizes, int n_in,
                              void* d_out, int out_size, void* d_ws, size_t ws_size,
                              hipStream_t stream)
{
    const float* z     = (const float*)d_in[0];
    const float* in_w  = (const float*)d_in[1];
    const float* in_b  = (const float*)d_in[2];
    const float* out_w = (const float*)d_in[3];
    const float* out_b = (const float*)d_in[4];
    const float* cb    = (const float*)d_in[5];
    float* out = (float*)d_out;
    float* ws  = (float*)d_ws;

    k_prep<<<dim3(126), dim3(256), 0, stream>>>(in_w, out_w, out_b, cb, ws);
    k_pool_proj<<<dim3(16, 32), dim3(512), 0, stream>>>(z, in_w, in_b, ws);
    k_vq<0><<<dim3(8192 / 64), dim3(512), 0, stream>>>(cb, ws, out);
    k_vq<1><<<dim3(16384 / 64), dim3(512), 0, stream>>>(cb, ws, out);
    k_vq<2><<<dim3(32768 / 64), dim3(512), 0, stream>>>(cb, ws, out);
    k_vq<3><<<dim3(65536 / 64), dim3(512), 0, stream>>>(cb, ws, out);
    k_zq<<<dim3(4096), dim3(256), 0, stream>>>(out_w, ws, out);
}